// Round 1
// baseline (649.282 us; speedup 1.0000x reference)
//
#include <hip/hip_runtime.h>

// GAT layer, N=8192, H=4, d=128.
// Key identity: softmax_j(src_i + tgt_j) over masked j == adj-weighted
// normalization of w_j = exp(tgt_j); src cancels. So:
//   out[i,d] = 0.25 * sum_h ( (adj @ (w_h*ht_h))[i,d] / (adj @ w_h)[i] )
// Pipeline:
//   k0: Wt = W^T (fp32)                      [for coalesced B staging in k1]
//   k1: HT = leakyrelu(h @ W) bf16 via MFMA  [8192 x 512]
//   k2: tgt/exp per row, build Yt bf16       [528 x 8192]  (Y transposed)
//       rows 0..511: w[g,j]*ht[j,g,d]; rows 512..515: w[g,j]; 516..527: 0
//   k3: C = adj @ Y (bf16 MFMA, fused int32->bf16 convert of adj),
//       grid (5,64): cb<4 numerator 128-wide, cb==4 denominators 16-wide
//   k4: out = 0.25 * sum_g C[:,g*128+d]/S[g,:]
// ws requirement: ~34.5 MB.

typedef unsigned short u16;
typedef unsigned int u32;
using bf16x8 = __attribute__((ext_vector_type(8))) short;
using f32x4  = __attribute__((ext_vector_type(4))) float;

__device__ __forceinline__ u16 f2bf(float f) {
  u32 u = __float_as_uint(f);
  u32 r = (u + 0x7FFFu + ((u >> 16) & 1u)) >> 16;  // RNE
  return (u16)r;
}
__device__ __forceinline__ float bf2f(u16 u) {
  return __uint_as_float(((u32)u) << 16);
}

// ---------------- k0: transpose W [256][512] -> Wt [512][256] ----------------
__global__ void transpose_w(const float* __restrict__ W, float* __restrict__ Wt) {
  __shared__ float tile[32][33];
  int cb = blockIdx.x * 32;  // 0..511 (16 blocks)
  int kb = blockIdx.y * 32;  // 0..255 (8 blocks)
  int tc = threadIdx.x & 31;
  int tr = threadIdx.x >> 5;  // 0..7
  for (int p = 0; p < 32; p += 8)
    tile[tr + p][tc] = W[(size_t)(kb + tr + p) * 512 + cb + tc];
  __syncthreads();
  for (int p = 0; p < 32; p += 8)
    Wt[(size_t)(cb + tr + p) * 256 + kb + tc] = tile[tc][tr + p];
}

// ---------------- k1: HT = leaky(h @ W), bf16 out [8192][512] ----------------
// block 256 thr (4 waves, 2x2 wave grid, wave tile 64x64 = 4x4 MFMA tiles)
__global__ void ht_gemm(const float* __restrict__ h, const float* __restrict__ Wt,
                        u16* __restrict__ HT) {
  __shared__ __align__(16) u16 Abuf[128 * 32];
  __shared__ __align__(16) u16 Bbuf[128 * 32];
  int tid = threadIdx.x;
  int cb = blockIdx.x, rb = blockIdx.y;
  int r0 = rb * 128, c0 = cb * 128;
  int lane = tid & 63, wv = tid >> 6;
  int wr = wv >> 1, wc = wv & 1;
  int mrow = lane & 15, q = lane >> 4;
  int ch = tid & 7, m0 = tid >> 3;

  f32x4 acc[4][4];
#pragma unroll
  for (int i = 0; i < 4; i++)
#pragma unroll
    for (int j = 0; j < 4; j++) acc[i][j] = f32x4{0.f, 0.f, 0.f, 0.f};

  for (int kt = 0; kt < 256; kt += 32) {
    __syncthreads();
#pragma unroll
    for (int mp = 0; mp < 128; mp += 32) {
      int m = m0 + mp;
      float4 v = *(const float4*)(&h[(size_t)(r0 + m) * 256 + kt + ch * 4]);
      uint2 p;
      p.x = (u32)f2bf(v.x) | ((u32)f2bf(v.y) << 16);
      p.y = (u32)f2bf(v.z) | ((u32)f2bf(v.w) << 16);
      *(uint2*)(&Abuf[m * 32 + ch * 4]) = p;
      float4 u = *(const float4*)(&Wt[(size_t)(c0 + m) * 256 + kt + ch * 4]);
      uint2 r;
      r.x = (u32)f2bf(u.x) | ((u32)f2bf(u.y) << 16);
      r.y = (u32)f2bf(u.z) | ((u32)f2bf(u.w) << 16);
      *(uint2*)(&Bbuf[m * 32 + ch * 4]) = r;
    }
    __syncthreads();
    bf16x8 af[4], bfv[4];
#pragma unroll
    for (int i = 0; i < 4; i++)
      af[i] = *(const bf16x8*)(&Abuf[(wr * 64 + i * 16 + mrow) * 32 + q * 8]);
#pragma unroll
    for (int j = 0; j < 4; j++)
      bfv[j] = *(const bf16x8*)(&Bbuf[(wc * 64 + j * 16 + mrow) * 32 + q * 8]);
#pragma unroll
    for (int i = 0; i < 4; i++)
#pragma unroll
      for (int j = 0; j < 4; j++)
        acc[i][j] = __builtin_amdgcn_mfma_f32_16x16x32_bf16(af[i], bfv[j], acc[i][j], 0, 0, 0);
  }
  // epilogue: leaky relu, bf16 store. C layout: col=lane&15, row=(lane>>4)*4+reg
#pragma unroll
  for (int i = 0; i < 4; i++)
#pragma unroll
    for (int j = 0; j < 4; j++)
#pragma unroll
      for (int r = 0; r < 4; r++) {
        int gi = r0 + wr * 64 + i * 16 + q * 4 + r;
        int gc = c0 + wc * 64 + j * 16 + mrow;
        float v = acc[i][j][r];
        v = v >= 0.f ? v : 0.1f * v;
        HT[(size_t)gi * 512 + gc] = f2bf(v);
      }
}

// ---------------- k2: build Yt [528][8192] bf16 ----------------
// block: 64 rows of HT, 256 threads; grid 128
__global__ void build_yt(const u16* __restrict__ HT, const float* __restrict__ a,
                         u16* __restrict__ Yt) {
  __shared__ u16 sht[64 * 512];
  __shared__ float swv[64 * 4];
  __shared__ float sa[4 * 128];
  int t = threadIdx.x;
  int j0 = blockIdx.x * 64;
  for (int i = t; i < 512; i += 256) {
    int g = i >> 7, d = i & 127;
    sa[i] = a[g * 256 + 128 + d];  // second half of a per head
  }
  for (int p = 0; p < 16; ++p) {
    int el = (t + 256 * p) * 8;
    *(uint4*)(&sht[el]) = *(const uint4*)(&HT[(size_t)j0 * 512 + el]);
  }
  __syncthreads();
  {
    int jl = t >> 2, g = t & 3;
    float acc = 0.f;
    for (int d = 0; d < 128; ++d)
      acc += bf2f(sht[jl * 512 + g * 128 + d]) * sa[g * 128 + d];
    swv[jl * 4 + g] = __expf(acc);
  }
  __syncthreads();
  for (int c = t; c < 512; c += 256) {
    int g = c >> 7;
    for (int j8 = 0; j8 < 64; j8 += 8) {
      u32 pk[4];
#pragma unroll
      for (int u = 0; u < 4; ++u) {
        float v0 = bf2f(sht[(j8 + 2 * u) * 512 + c]) * swv[(j8 + 2 * u) * 4 + g];
        float v1 = bf2f(sht[(j8 + 2 * u + 1) * 512 + c]) * swv[(j8 + 2 * u + 1) * 4 + g];
        pk[u] = (u32)f2bf(v0) | ((u32)f2bf(v1) << 16);
      }
      *(uint4*)(&Yt[(size_t)c * 8192 + j0 + j8]) = make_uint4(pk[0], pk[1], pk[2], pk[3]);
    }
  }
  if (t < 16) {  // rows 512..515 = w[g], 516..527 = 0
    int c = 512 + t;
    for (int j8 = 0; j8 < 64; j8 += 8) {
      u32 pk[4] = {0u, 0u, 0u, 0u};
      if (t < 4) {
#pragma unroll
        for (int u = 0; u < 4; ++u) {
          float v0 = swv[(j8 + 2 * u) * 4 + t];
          float v1 = swv[(j8 + 2 * u + 1) * 4 + t];
          pk[u] = (u32)f2bf(v0) | ((u32)f2bf(v1) << 16);
        }
      }
      *(uint4*)(&Yt[(size_t)c * 8192 + j0 + j8]) = make_uint4(pk[0], pk[1], pk[2], pk[3]);
    }
  }
}

// ---------------- k3: C = adj @ Y ----------------
// grid (5, 64): cb<4 -> 128x128 numerator tile (head cb); cb==4 -> 16-wide denom
__global__ void adj_gemm(const int* __restrict__ adj, const u16* __restrict__ Yt,
                         float* __restrict__ C, float* __restrict__ S) {
  __shared__ __align__(16) u16 Abuf[128 * 32];
  __shared__ __align__(16) u16 Bbuf[128 * 32];
  int tid = threadIdx.x;
  int cb = blockIdx.x, rb = blockIdx.y;
  int r0 = rb * 128;
  int lane = tid & 63, wv = tid >> 6;
  int mrow = lane & 15, q = lane >> 4;
  int ch = tid & 7, m0 = tid >> 3;   // A staging: 8 chunks x 32 rows/pass
  int bn0 = tid >> 2, bch = tid & 3; // B staging: 4 chunks x 64 rows/pass

  if (cb < 4) {
    int c0 = cb * 128;
    int wr = wv >> 1, wc = wv & 1;
    f32x4 acc[4][4];
#pragma unroll
    for (int i = 0; i < 4; i++)
#pragma unroll
      for (int j = 0; j < 4; j++) acc[i][j] = f32x4{0.f, 0.f, 0.f, 0.f};

    for (int kt = 0; kt < 8192; kt += 32) {
      __syncthreads();
#pragma unroll
      for (int mp = 0; mp < 128; mp += 32) {
        int m = m0 + mp;
        int4 v = *(const int4*)(&adj[(size_t)(r0 + m) * 8192 + kt + ch * 4]);
        uint2 p;  // adj in {0,1}: bf16 bits = x * 0x3F80, packed pairwise
        p.x = 16256u * ((u32)v.x | ((u32)v.y << 16));
        p.y = 16256u * ((u32)v.z | ((u32)v.w << 16));
        *(uint2*)(&Abuf[m * 32 + ch * 4]) = p;
      }
#pragma unroll
      for (int np = 0; np < 128; np += 64) {
        int n = bn0 + np;
        uint4 v = *(const uint4*)(&Yt[(size_t)(c0 + n) * 8192 + kt + bch * 8]);
        *(uint4*)(&Bbuf[n * 32 + bch * 8]) = v;
      }
      __syncthreads();
      bf16x8 af[4], bfv[4];
#pragma unroll
      for (int i = 0; i < 4; i++)
        af[i] = *(const bf16x8*)(&Abuf[(wr * 64 + i * 16 + mrow) * 32 + q * 8]);
#pragma unroll
      for (int j = 0; j < 4; j++)
        bfv[j] = *(const bf16x8*)(&Bbuf[(wc * 64 + j * 16 + mrow) * 32 + q * 8]);
#pragma unroll
      for (int i = 0; i < 4; i++)
#pragma unroll
        for (int j = 0; j < 4; j++)
          acc[i][j] = __builtin_amdgcn_mfma_f32_16x16x32_bf16(af[i], bfv[j], acc[i][j], 0, 0, 0);
    }
#pragma unroll
    for (int i = 0; i < 4; i++)
#pragma unroll
      for (int j = 0; j < 4; j++)
#pragma unroll
        for (int r = 0; r < 4; r++) {
          int gi = r0 + wr * 64 + i * 16 + q * 4 + r;
          int gc = c0 + wc * 64 + j * 16 + mrow;
          C[(size_t)gi * 512 + gc] = acc[i][j][r];
        }
  } else {
    // denominator path: B = Yt rows 512..527 (w0..w3, 12 zero cols)
    f32x4 acc2[2];
    acc2[0] = f32x4{0.f, 0.f, 0.f, 0.f};
    acc2[1] = f32x4{0.f, 0.f, 0.f, 0.f};
    for (int kt = 0; kt < 8192; kt += 32) {
      __syncthreads();
#pragma unroll
      for (int mp = 0; mp < 128; mp += 32) {
        int m = m0 + mp;
        int4 v = *(const int4*)(&adj[(size_t)(r0 + m) * 8192 + kt + ch * 4]);
        uint2 p;
        p.x = 16256u * ((u32)v.x | ((u32)v.y << 16));
        p.y = 16256u * ((u32)v.z | ((u32)v.w << 16));
        *(uint2*)(&Abuf[m * 32 + ch * 4]) = p;
      }
      if (tid < 64) {
        int n = tid >> 2;  // 0..15
        uint4 v = *(const uint4*)(&Yt[(size_t)(512 + n) * 8192 + kt + (tid & 3) * 8]);
        *(uint4*)(&Bbuf[n * 32 + (tid & 3) * 8]) = v;
      }
      __syncthreads();
      bf16x8 bfv = *(const bf16x8*)(&Bbuf[mrow * 32 + q * 8]);
#pragma unroll
      for (int t2 = 0; t2 < 2; t2++) {
        bf16x8 af = *(const bf16x8*)(&Abuf[((wv * 2 + t2) * 16 + mrow) * 32 + q * 8]);
        acc2[t2] = __builtin_amdgcn_mfma_f32_16x16x32_bf16(af, bfv, acc2[t2], 0, 0, 0);
      }
    }
#pragma unroll
    for (int t2 = 0; t2 < 2; t2++)
#pragma unroll
      for (int r = 0; r < 4; r++) {
        int gi = r0 + (wv * 2 + t2) * 16 + q * 4 + r;
        if (mrow < 4) S[(size_t)mrow * 8192 + gi] = acc2[t2][r];
      }
  }
}

// ---------------- k4: out = 0.25 * sum_g C[:,g*128+d]/S[g,:] ----------------
__global__ void finalize_gat(const float* __restrict__ C, const float* __restrict__ S,
                             float* __restrict__ out) {
  int idx = blockIdx.x * 256 + threadIdx.x;
  int i = idx >> 7, d = idx & 127;
  float s = 0.f;
#pragma unroll
  for (int g = 0; g < 4; ++g)
    s += C[(size_t)i * 512 + g * 128 + d] / S[(size_t)g * 8192 + i];
  out[idx] = 0.25f * s;
}

extern "C" void kernel_launch(void* const* d_in, const int* in_sizes, int n_in,
                              void* d_out, int out_size, void* d_ws, size_t ws_size,
                              hipStream_t stream) {
  const float* h   = (const float*)d_in[0];
  const int*   adj = (const int*)d_in[1];
  const float* W   = (const float*)d_in[2];
  const float* a   = (const float*)d_in[3];
  float* out = (float*)d_out;
  char* ws = (char*)d_ws;
  // ws layout (16B aligned): Wt 512K | HT 8M | Yt 8.65M | C 16M | S 128K  (~34.5 MB)
  float* Wt = (float*)(ws + 0);
  u16*   HT = (u16*)(ws + 524288);
  u16*   Yt = (u16*)(ws + 8912896);
  float* C  = (float*)(ws + 17563648);
  float* S  = (float*)(ws + 34340864);

  transpose_w<<<dim3(16, 8), 256, 0, stream>>>(W, Wt);
  ht_gemm<<<dim3(4, 64), 256, 0, stream>>>(h, Wt, HT);
  build_yt<<<dim3(128), 256, 0, stream>>>(HT, a, Yt);
  adj_gemm<<<dim3(5, 64), 256, 0, stream>>>(adj, Yt, C, S);
  finalize_gat<<<dim3(4096), 256, 0, stream>>>(C, S, out);
}

// Round 2
// 578.372 us; speedup vs baseline: 1.1226x; 1.1226x over previous
//
#include <hip/hip_runtime.h>

// GAT layer, N=8192, H=4, d=128.
// softmax_j(src_i + tgt_j) masked == adj-normalized w_j = exp(tgt_j); src cancels:
//   out[i,d] = 0.25 * sum_h ( (adj @ (w_h*ht_h))[i,d] / (adj @ w_h)[i] )
// Pipeline:
//   k0: Wt = W^T
//   k1: HT = leakyrelu(h @ W) bf16 MFMA        [8192 x 512]
//   k2: build Yt bf16 [528][8192]: rows 0..511 = w[g,j]*ht[j,g,d];
//       512..515 = w[g,j]; 516..527 = 0.  (coalesced transposed stores)
//   k3: C += adj @ Y, K-split 4 via fp32 atomics, grid (4,64,4);
//       denominator (16 cols) fused into cb==0 blocks' wc==0 waves.
//   k4: out = 0.25 * sum_g C[:,g*128+d]/S[g,:]
// ws ~33 MB (same layout as round 1).

typedef unsigned short u16;
typedef unsigned int u32;
using bf16x8 = __attribute__((ext_vector_type(8))) short;
using f32x4  = __attribute__((ext_vector_type(4))) float;

typedef const void __attribute__((address_space(1))) gas_void;
typedef void __attribute__((address_space(3))) las_void;
#define GLD16(g, l) __builtin_amdgcn_global_load_lds((gas_void*)(g), (las_void*)(l), 16, 0, 0)

__device__ __forceinline__ u16 f2bf(float f) {
  u32 u = __float_as_uint(f);
  return (u16)((u + 0x7FFFu + ((u >> 16) & 1u)) >> 16);  // RNE
}
__device__ __forceinline__ float bf2f(u16 u) {
  return __uint_as_float(((u32)u) << 16);
}

// ---------------- k0: transpose W [256][512] -> Wt [512][256] ----------------
__global__ void transpose_w(const float* __restrict__ W, float* __restrict__ Wt) {
  __shared__ float tile[32][33];
  int cb = blockIdx.x * 32, kb = blockIdx.y * 32;
  int tc = threadIdx.x & 31, tr = threadIdx.x >> 5;
  for (int p = 0; p < 32; p += 8)
    tile[tr + p][tc] = W[(size_t)(kb + tr + p) * 512 + cb + tc];
  __syncthreads();
  for (int p = 0; p < 32; p += 8)
    Wt[(size_t)(cb + tr + p) * 256 + kb + tc] = tile[tc][tr + p];
}

// ---------------- k1: HT = leaky(h @ W), bf16 out [8192][512] ----------------
__global__ void ht_gemm(const float* __restrict__ h, const float* __restrict__ Wt,
                        u16* __restrict__ HT) {
  __shared__ __align__(16) u16 Abuf[128 * 40];
  __shared__ __align__(16) u16 Bbuf[128 * 40];
  int tid = threadIdx.x;
  int cb = blockIdx.x, rb = blockIdx.y;
  int r0 = rb * 128, c0 = cb * 128;
  int lane = tid & 63, wv = tid >> 6;
  int wr = wv >> 1, wc = wv & 1;
  int mrow = lane & 15, q = lane >> 4;
  int ch = tid & 7, m0 = tid >> 3;

  f32x4 acc[4][4];
#pragma unroll
  for (int i = 0; i < 4; i++)
#pragma unroll
    for (int j = 0; j < 4; j++) acc[i][j] = f32x4{0.f, 0.f, 0.f, 0.f};

  for (int kt = 0; kt < 256; kt += 32) {
    __syncthreads();
#pragma unroll
    for (int mp = 0; mp < 128; mp += 32) {
      int m = m0 + mp;
      float4 v = *(const float4*)(&h[(size_t)(r0 + m) * 256 + kt + ch * 4]);
      uint2 p;
      p.x = (u32)f2bf(v.x) | ((u32)f2bf(v.y) << 16);
      p.y = (u32)f2bf(v.z) | ((u32)f2bf(v.w) << 16);
      *(uint2*)(&Abuf[m * 40 + ch * 4]) = p;
      float4 u = *(const float4*)(&Wt[(size_t)(c0 + m) * 256 + kt + ch * 4]);
      uint2 r;
      r.x = (u32)f2bf(u.x) | ((u32)f2bf(u.y) << 16);
      r.y = (u32)f2bf(u.z) | ((u32)f2bf(u.w) << 16);
      *(uint2*)(&Bbuf[m * 40 + ch * 4]) = r;
    }
    __syncthreads();
    bf16x8 af[4], bfv[4];
#pragma unroll
    for (int i = 0; i < 4; i++)
      af[i] = *(const bf16x8*)(&Abuf[(wr * 64 + i * 16 + mrow) * 40 + q * 8]);
#pragma unroll
    for (int j = 0; j < 4; j++)
      bfv[j] = *(const bf16x8*)(&Bbuf[(wc * 64 + j * 16 + mrow) * 40 + q * 8]);
#pragma unroll
    for (int i = 0; i < 4; i++)
#pragma unroll
      for (int j = 0; j < 4; j++)
        acc[i][j] = __builtin_amdgcn_mfma_f32_16x16x32_bf16(af[i], bfv[j], acc[i][j], 0, 0, 0);
  }
#pragma unroll
  for (int i = 0; i < 4; i++)
#pragma unroll
    for (int j = 0; j < 4; j++)
#pragma unroll
      for (int r = 0; r < 4; r++) {
        int gi = r0 + wr * 64 + i * 16 + q * 4 + r;
        int gc = c0 + wc * 64 + j * 16 + mrow;
        float v = acc[i][j][r];
        v = v >= 0.f ? v : 0.1f * v;
        HT[(size_t)gi * 512 + gc] = f2bf(v);
      }
}

// ---------------- k2: build Yt [528][8192] bf16, coalesced stores ----------------
__global__ void build_yt(const u16* __restrict__ HT, const float* __restrict__ a,
                         u16* __restrict__ Yt) {
  __shared__ u16 sht[64][528];  // pad: row stride 1056 B (16B-aligned, bank stride 8)
  __shared__ float swv[64 * 4];
  __shared__ float sa[512];
  int t = threadIdx.x;
  int j0 = blockIdx.x * 64;
  for (int i = t; i < 512; i += 256) {
    int g = i >> 7, d = i & 127;
    sa[i] = a[g * 256 + 128 + d];
  }
#pragma unroll
  for (int p = 0; p < 16; ++p) {
    int el = t + 256 * p;
    int row = el >> 6, col8 = el & 63;
    *(uint4*)(&sht[row][col8 * 8]) = *(const uint4*)(&HT[(size_t)(j0 + row) * 512 + col8 * 8]);
  }
  __syncthreads();
  {
    int jl = t >> 2, g = t & 3;
    float acc = 0.f;
    for (int d = 0; d < 128; ++d)
      acc += bf2f(sht[jl][g * 128 + d]) * sa[g * 128 + d];
    swv[jl * 4 + g] = __expf(acc);
  }
  __syncthreads();
  // transposed store: thread t -> col c = pass*32 + (t>>3), j-octet (t&7)
  int oj = (t & 7) * 8, oc = t >> 3;
  for (int pass = 0; pass < 17; ++pass) {
    int c = pass * 32 + oc;
    if (c >= 528) break;
    u32 pk[4] = {0u, 0u, 0u, 0u};
    if (c < 512) {
      int g = c >> 7;
#pragma unroll
      for (int u = 0; u < 4; ++u) {
        int j = oj + 2 * u;
        float v0 = bf2f(sht[j][c]) * swv[j * 4 + g];
        float v1 = bf2f(sht[j + 1][c]) * swv[(j + 1) * 4 + g];
        pk[u] = (u32)f2bf(v0) | ((u32)f2bf(v1) << 16);
      }
    } else if (c < 516) {
      int g = c - 512;
#pragma unroll
      for (int u = 0; u < 4; ++u) {
        int j = oj + 2 * u;
        float v0 = swv[j * 4 + g];
        float v1 = swv[(j + 1) * 4 + g];
        pk[u] = (u32)f2bf(v0) | ((u32)f2bf(v1) << 16);
      }
    }
    *(uint4*)(&Yt[(size_t)c * 8192 + j0 + oj]) = make_uint4(pk[0], pk[1], pk[2], pk[3]);
  }
}

// ---------------- k3: C += adj @ Y  (K-split 4, atomics) ----------------
// grid (4, 64, 4): cb = head column block, rb = row band, kh = K quarter.
// cb==0 blocks also accumulate denominators S (16-col MFMA on wc==0 waves).
__global__ __launch_bounds__(256) void adj_gemm(const int* __restrict__ adj,
                                                const u16* __restrict__ Yt,
                                                float* __restrict__ C,
                                                float* __restrict__ S) {
  __shared__ __align__(16) u16 Abuf[128 * 40];  // stride-40 pad (2-way conflicts = free)
  __shared__ __align__(16) u16 Bbuf[128 * 32];  // global_load_lds: contiguous, stride 32
  __shared__ __align__(16) u16 Bden[16 * 32];
  int tid = threadIdx.x;
  int cb = blockIdx.x, rb = blockIdx.y, kh = blockIdx.z;
  int r0 = rb * 128, c0 = cb * 128, k0 = kh * 2048;
  int lane = tid & 63, wv = tid >> 6;
  int wr = wv >> 1, wc = wv & 1;
  int mrow = lane & 15, q = lane >> 4;
  int ch = tid & 7, m0 = tid >> 3;
  int brow = lane >> 2, bq = lane & 3;
  bool do_den = (cb == 0) && (wc == 0);

  f32x4 acc[4][4];
#pragma unroll
  for (int i = 0; i < 4; i++)
#pragma unroll
    for (int j = 0; j < 4; j++) acc[i][j] = f32x4{0.f, 0.f, 0.f, 0.f};
  f32x4 accD[4];
#pragma unroll
  for (int i = 0; i < 4; i++) accD[i] = f32x4{0.f, 0.f, 0.f, 0.f};

  for (int kt = k0; kt < k0 + 2048; kt += 32) {
    __syncthreads();
    // A: int32 adj -> bf16, stride-40 LDS
#pragma unroll
    for (int mp = 0; mp < 128; mp += 32) {
      int m = m0 + mp;
      int4 v = *(const int4*)(&adj[(size_t)(r0 + m) * 8192 + kt + ch * 4]);
      uint2 p;  // {0,1} -> bf16 bits (0x3F80 * x), packed pairwise
      p.x = 16256u * ((u32)v.x | ((u32)v.y << 16));
      p.y = 16256u * ((u32)v.z | ((u32)v.w << 16));
      *(uint2*)(&Abuf[m * 40 + ch * 4]) = p;
    }
    // B: Yt bf16 via async global->LDS, 16B/lane; wave stages 16 rows/call
    GLD16(&Yt[(size_t)(c0 + wv * 16 + brow) * 8192 + kt + bq * 8],
          &Bbuf[(wv * 16) * 32]);
    GLD16(&Yt[(size_t)(c0 + 64 + wv * 16 + brow) * 8192 + kt + bq * 8],
          &Bbuf[(64 + wv * 16) * 32]);
    if (cb == 0 && wv == 0)
      GLD16(&Yt[(size_t)(512 + brow) * 8192 + kt + bq * 8], Bden);
    __syncthreads();
    bf16x8 af[4], bfv[4];
#pragma unroll
    for (int i = 0; i < 4; i++)
      af[i] = *(const bf16x8*)(&Abuf[(wr * 64 + i * 16 + mrow) * 40 + q * 8]);
#pragma unroll
    for (int j = 0; j < 4; j++)
      bfv[j] = *(const bf16x8*)(&Bbuf[(wc * 64 + j * 16 + mrow) * 32 + q * 8]);
#pragma unroll
    for (int i = 0; i < 4; i++)
#pragma unroll
      for (int j = 0; j < 4; j++)
        acc[i][j] = __builtin_amdgcn_mfma_f32_16x16x32_bf16(af[i], bfv[j], acc[i][j], 0, 0, 0);
    if (do_den) {
      bf16x8 bd = *(const bf16x8*)(&Bden[mrow * 32 + q * 8]);
#pragma unroll
      for (int i = 0; i < 4; i++)
        accD[i] = __builtin_amdgcn_mfma_f32_16x16x32_bf16(af[i], bd, accD[i], 0, 0, 0);
    }
  }
#pragma unroll
  for (int i = 0; i < 4; i++)
#pragma unroll
    for (int j = 0; j < 4; j++)
#pragma unroll
      for (int r = 0; r < 4; r++) {
        int gi = r0 + wr * 64 + i * 16 + q * 4 + r;
        int gc = c0 + wc * 64 + j * 16 + mrow;
        atomicAdd(&C[(size_t)gi * 512 + gc], acc[i][j][r]);
      }
  if (do_den && mrow < 4) {
#pragma unroll
    for (int i = 0; i < 4; i++)
#pragma unroll
      for (int r = 0; r < 4; r++) {
        int gi = r0 + wr * 64 + i * 16 + q * 4 + r;
        atomicAdd(&S[(size_t)mrow * 8192 + gi], accD[i][r]);
      }
  }
}

// ---------------- k4: out = 0.25 * sum_g C[:,g*128+d]/S[g,:] ----------------
__global__ void finalize_gat(const float* __restrict__ C, const float* __restrict__ S,
                             float* __restrict__ out) {
  int idx = blockIdx.x * 256 + threadIdx.x;
  int i = idx >> 7, d = idx & 127;
  float s = 0.f;
#pragma unroll
  for (int g = 0; g < 4; ++g)
    s += C[(size_t)i * 512 + g * 128 + d] / S[(size_t)g * 8192 + i];
  out[idx] = 0.25f * s;
}

extern "C" void kernel_launch(void* const* d_in, const int* in_sizes, int n_in,
                              void* d_out, int out_size, void* d_ws, size_t ws_size,
                              hipStream_t stream) {
  const float* h   = (const float*)d_in[0];
  const int*   adj = (const int*)d_in[1];
  const float* W   = (const float*)d_in[2];
  const float* a   = (const float*)d_in[3];
  float* out = (float*)d_out;
  char* ws = (char*)d_ws;
  // ws layout: Wt 512K | HT 8M | Yt 8.65M | C 16M | S 128K  (~33 MB)
  float* Wt = (float*)(ws + 0);
  u16*   HT = (u16*)(ws + 524288);
  u16*   Yt = (u16*)(ws + 8912896);
  float* C  = (float*)(ws + 17563648);
  float* S  = (float*)(ws + 34340864);

  hipMemsetAsync(C, 0, (size_t)8192 * 512 * 4, stream);
  hipMemsetAsync(S, 0, (size_t)4 * 8192 * 4, stream);
  transpose_w<<<dim3(16, 8), 256, 0, stream>>>(W, Wt);
  ht_gemm<<<dim3(4, 64), 256, 0, stream>>>(h, Wt, HT);
  build_yt<<<dim3(128), 256, 0, stream>>>(HT, a, Yt);
  adj_gemm<<<dim3(4, 64, 4), 256, 0, stream>>>(adj, Yt, C, S);
  finalize_gat<<<dim3(4096), 256, 0, stream>>>(C, S, out);
}